// Round 1
// baseline (968.663 us; speedup 1.0000x reference)
//
#include <hip/hip_runtime.h>
#include <math.h>

#define BATCH 8
#define CIN   128
#define COUT  128
#define HH    112
#define WW    112
#define HW    (HH*WW)          // 12544
#define KK9   9
#define BKHW  (BATCH*KK9*HW)   // 903168

// ---------- prep: w[co][c][3][3] -> wt[(c*9+k)][co]  (coalesced-over-co GEMM reads)
__global__ __launch_bounds__(256) void prep_wt(const float* __restrict__ w,
                                               float* __restrict__ wt) {
    int id = blockIdx.x * 256 + threadIdx.x;   // 147456 total
    int co = id & 127;
    int ck = id >> 7;                          // c*9+k
    wt[id] = w[co * 1152 + ck];
}

// ---------- kernel 1: fused 27-channel 3x3 conv -> dy, dx, mask(=2*sigmoid)
__global__ __launch_bounds__(256) void offmask_kernel(
    const float* __restrict__ x,
    const float* __restrict__ offw, const float* __restrict__ offb,
    const float* __restrict__ modw, const float* __restrict__ modb,
    float* __restrict__ dy, float* __restrict__ dx, float* __restrict__ mask)
{
    __shared__ float wl[32 * 9 * 28];          // [c][kk][ch pad 28]

    int p   = blockIdx.x * 256 + threadIdx.x;  // 100352 pixels exactly
    int b   = p / HW;
    int rem = p - b * HW;
    int ho  = rem / WW;
    int wo  = rem - ho * WW;

    float4 acc4[7];
    #pragma unroll
    for (int g = 0; g < 7; ++g) acc4[g] = make_float4(0.f, 0.f, 0.f, 0.f);

    for (int cb = 0; cb < 4; ++cb) {
        int cbase = cb * 32;
        __syncthreads();
        for (int idx = threadIdx.x; idx < 32 * 9 * 27; idx += 256) {
            int c  = idx / 243;
            int r  = idx - c * 243;
            int kk = r / 27;
            int ch = r - kk * 27;
            float v;
            if (ch < 18) v = offw[(ch * CIN + cbase + c) * 9 + kk];
            else         v = modw[((ch - 18) * CIN + cbase + c) * 9 + kk];
            wl[(c * 9 + kk) * 28 + ch] = v;
        }
        for (int idx = threadIdx.x; idx < 32 * 9; idx += 256)
            wl[idx * 28 + 27] = 0.f;           // keep pad lane clean
        __syncthreads();

        for (int c = 0; c < 32; ++c) {
            const float* xp = x + (size_t)((b * CIN + cbase + c) * HH) * WW;
            float xv[9];
            #pragma unroll
            for (int ki = 0; ki < 3; ++ki) {
                int y = ho - 1 + ki;
                #pragma unroll
                for (int kj = 0; kj < 3; ++kj) {
                    int xx = wo - 1 + kj;
                    bool in = ((unsigned)y < HH) && ((unsigned)xx < WW);
                    xv[ki * 3 + kj] = in ? xp[y * WW + xx] : 0.f;
                }
            }
            #pragma unroll
            for (int kk = 0; kk < 9; ++kk) {
                float xk = xv[kk];
                const float4* wr = (const float4*)&wl[(c * 9 + kk) * 28];
                #pragma unroll
                for (int g = 0; g < 7; ++g) {
                    float4 wv = wr[g];
                    acc4[g].x += xk * wv.x;
                    acc4[g].y += xk * wv.y;
                    acc4[g].z += xk * wv.z;
                    acc4[g].w += xk * wv.w;
                }
            }
        }
    }

    const float* acc = (const float*)acc4;
    int idxp_base = (b * KK9) * HW + ho * WW + wo;
    #pragma unroll
    for (int k = 0; k < 9; ++k) {
        float dyv = acc[2 * k]     + offb[2 * k];
        float dxv = acc[2 * k + 1] + offb[2 * k + 1];
        float mv  = acc[18 + k]    + modb[k];
        float m   = 2.f / (1.f + expf(-mv));
        int idxp = idxp_base + k * HW;
        dy[idxp]   = dyv;
        dx[idxp]   = dxv;
        mask[idxp] = m;
    }
}

// ---------- kernel 2: bilinear sample (masked) into LDS + fp32 GEMM
#define FMA8(ai, sv) { acc[ai].x += (sv)*w4.x; acc[ai].y += (sv)*w4.y; \
                       acc[ai].z += (sv)*w4.z; acc[ai].w += (sv)*w4.w; }

__global__ __launch_bounds__(256) void deform_main(
    const float* __restrict__ x,
    const float* __restrict__ dy, const float* __restrict__ dx,
    const float* __restrict__ mask,
    const float* __restrict__ wt, const float* __restrict__ bias,
    float* __restrict__ out)
{
    __shared__ float sm[128 * 68];     // [c][px pad 68] masked samples
    __shared__ int   caddr[4][64];
    __shared__ float cwgt[4][64];

    const int tid    = threadIdx.x;
    const int wstart = blockIdx.x * 48;     // tiles at wo=0 and wo=48 (overlap writes identical)
    const int ho     = blockIdx.y;
    const int b      = blockIdx.z;

    const int pxl  = tid & 63;   // sampling: lane = pixel
    const int cset = tid >> 6;   // 0..3 -> 32 channels each
    const int co_g = tid >> 3;   // GEMM: 32 co-groups (4 co each)
    const int px_g = tid & 7;    // 8 px-groups (8 px each)

    float4 acc[8];
    #pragma unroll
    for (int i = 0; i < 8; ++i) acc[i] = make_float4(0.f, 0.f, 0.f, 0.f);

    const float* xb = x + (size_t)b * CIN * HW;

    for (int k = 0; k < 9; ++k) {
        // --- per-pixel corner addresses + (bilinear * valid * mask) weights
        if (tid < 64) {
            int wo = wstart + pxl;
            int idxp = (b * KK9 + k) * HW + ho * WW + wo;
            float dyv = dy[idxp], dxv = dx[idxp], mv = mask[idxp];
            float ys = (float)(ho - 1 + (k / 3)) + dyv;
            float xs = (float)(wo - 1 + (k % 3)) + dxv;
            float fy = floorf(ys), fx = floorf(xs);
            int   y0 = (int)fy,   x0 = (int)fx;
            float ly = ys - fy,   lx = xs - fx;
            #pragma unroll
            for (int j = 0; j < 4; ++j) {
                int yi = y0 + (j >> 1), xi = x0 + (j & 1);
                bool valid = ((unsigned)yi < HH) && ((unsigned)xi < WW);
                float wj = ((j >> 1) ? ly : 1.f - ly) * ((j & 1) ? lx : 1.f - lx) * mv;
                caddr[j][pxl] = valid ? (yi * WW + xi) : 0;
                cwgt[j][pxl]  = valid ? wj : 0.f;
            }
        }
        __syncthreads();   // also separates prev-iter GEMM sm reads from new sm writes

        // --- gather-sample 128 channels x 64 px into LDS
        {
            int   a0 = caddr[0][pxl], a1 = caddr[1][pxl], a2 = caddr[2][pxl], a3 = caddr[3][pxl];
            float w0 = cwgt[0][pxl],  w1 = cwgt[1][pxl],  w2 = cwgt[2][pxl],  w3 = cwgt[3][pxl];
            const float* xc = xb + (size_t)(cset * 32) * HW;
            float* smp = sm + (cset * 32) * 68 + pxl;
            #pragma unroll 4
            for (int ci = 0; ci < 32; ++ci) {
                float v = xc[a0] * w0 + xc[a1] * w1 + xc[a2] * w2 + xc[a3] * w3;
                smp[0] = v;
                smp += 68;
                xc  += HW;
            }
        }
        __syncthreads();

        // --- fp32 GEMM: acc[4co x 8px] += wt[c*9+k][co] * sm[c][px]
        const float* wtk = wt + (size_t)k * 128 + co_g * 4;
        #pragma unroll 4
        for (int c = 0; c < 128; ++c) {
            float4 w4 = *(const float4*)(wtk + (size_t)c * 9 * 128);
            const float* smr = sm + c * 68 + px_g * 8;
            float4 s0 = *(const float4*)(smr);
            float4 s1 = *(const float4*)(smr + 4);
            FMA8(0, s0.x) FMA8(1, s0.y) FMA8(2, s0.z) FMA8(3, s0.w)
            FMA8(4, s1.x) FMA8(5, s1.y) FMA8(6, s1.z) FMA8(7, s1.w)
        }
    }

    // --- epilogue: + bias, scatter stores
    const float4 bco = *(const float4*)(bias + co_g * 4);
    #pragma unroll
    for (int i = 0; i < 8; ++i) {
        int wo = wstart + px_g * 8 + i;
        size_t obase = ((size_t)(b * COUT + co_g * 4) * HH + ho) * WW + wo;
        out[obase]          = acc[i].x + bco.x;
        out[obase + HW]     = acc[i].y + bco.y;
        out[obase + 2 * HW] = acc[i].z + bco.z;
        out[obase + 3 * HW] = acc[i].w + bco.w;
    }
}

extern "C" void kernel_launch(void* const* d_in, const int* in_sizes, int n_in,
                              void* d_out, int out_size, void* d_ws, size_t ws_size,
                              hipStream_t stream) {
    (void)in_sizes; (void)n_in; (void)out_size; (void)ws_size;
    const float* x    = (const float*)d_in[0];
    const float* offw = (const float*)d_in[1];
    const float* offb = (const float*)d_in[2];
    const float* modw = (const float*)d_in[3];
    const float* modb = (const float*)d_in[4];
    const float* w    = (const float*)d_in[5];
    const float* bias = (const float*)d_in[6];
    float* out = (float*)d_out;

    float* ws   = (float*)d_ws;
    float* dyp  = ws;
    float* dxp  = ws + (size_t)BKHW;
    float* mkp  = ws + (size_t)2 * BKHW;
    float* wtp  = ws + (size_t)3 * BKHW;   // 147456 floats; total ws use ~11.4 MB

    prep_wt<<<576, 256, 0, stream>>>(w, wtp);
    offmask_kernel<<<392, 256, 0, stream>>>(x, offw, offb, modw, modb, dyp, dxp, mkp);
    deform_main<<<dim3(2, 112, 8), 256, 0, stream>>>(x, dyp, dxp, mkp, wtp, bias, out);
}

// Round 2
// 750.393 us; speedup vs baseline: 1.2909x; 1.2909x over previous
//
#include <hip/hip_runtime.h>
#include <hip/hip_bf16.h>
#include <math.h>

#define BATCH 8
#define CIN   128
#define COUT  128
#define HH    112
#define WW    112
#define HW    (HH*WW)          // 12544
#define KK9   9
#define BKHW  (BATCH*KK9*HW)   // 903168

typedef short  bf16x8 __attribute__((ext_vector_type(8)));
typedef float  f32x4  __attribute__((ext_vector_type(4)));

static __device__ __forceinline__ unsigned f2bf(float f) {
    union { float f; unsigned u; } v; v.f = f;
    unsigned r = v.u + 0x7FFF + ((v.u >> 16) & 1);
    return r >> 16;
}

// ---------- prep: w[co][c][3][3] -> bf16 MFMA A-fragment order
// frag = (k*4+s)*8 + m ; lane holds co = m*16+(l&15), c = s*32+(l>>4)*8+j
__global__ __launch_bounds__(256) void prep_afrag(const float* __restrict__ w,
                                                  unsigned short* __restrict__ af) {
    int id   = blockIdx.x * 256 + threadIdx.x;   // 147456 total
    int j    = id & 7;
    int lane = (id >> 3) & 63;
    int m    = (id >> 9) & 7;
    int s    = (id >> 12) & 3;
    int k    = id >> 14;
    int co   = m * 16 + (lane & 15);
    int c    = s * 32 + (lane >> 4) * 8 + j;
    af[id] = (unsigned short)f2bf(w[(co * CIN + c) * 9 + k]);
}

// ---------- kernel 1: fused 27-channel 3x3 conv -> dy, dx, mask(=2*sigmoid)
__global__ __launch_bounds__(256) void offmask_kernel(
    const float* __restrict__ x,
    const float* __restrict__ offw, const float* __restrict__ offb,
    const float* __restrict__ modw, const float* __restrict__ modb,
    float* __restrict__ dy, float* __restrict__ dx, float* __restrict__ mask)
{
    __shared__ float wl[32 * 9 * 28];          // [c][kk][ch pad 28]

    int p   = blockIdx.x * 256 + threadIdx.x;  // 100352 pixels exactly
    int b   = p / HW;
    int rem = p - b * HW;
    int ho  = rem / WW;
    int wo  = rem - ho * WW;

    float4 acc4[7];
    #pragma unroll
    for (int g = 0; g < 7; ++g) acc4[g] = make_float4(0.f, 0.f, 0.f, 0.f);

    for (int cb = 0; cb < 4; ++cb) {
        int cbase = cb * 32;
        __syncthreads();
        for (int idx = threadIdx.x; idx < 32 * 9 * 27; idx += 256) {
            int c  = idx / 243;
            int r  = idx - c * 243;
            int kk = r / 27;
            int ch = r - kk * 27;
            float v;
            if (ch < 18) v = offw[(ch * CIN + cbase + c) * 9 + kk];
            else         v = modw[((ch - 18) * CIN + cbase + c) * 9 + kk];
            wl[(c * 9 + kk) * 28 + ch] = v;
        }
        for (int idx = threadIdx.x; idx < 32 * 9; idx += 256)
            wl[idx * 28 + 27] = 0.f;
        __syncthreads();

        for (int c = 0; c < 32; ++c) {
            const float* xp = x + (size_t)((b * CIN + cbase + c) * HH) * WW;
            float xv[9];
            #pragma unroll
            for (int ki = 0; ki < 3; ++ki) {
                int y = ho - 1 + ki;
                #pragma unroll
                for (int kj = 0; kj < 3; ++kj) {
                    int xx = wo - 1 + kj;
                    bool in = ((unsigned)y < HH) && ((unsigned)xx < WW);
                    xv[ki * 3 + kj] = in ? xp[y * WW + xx] : 0.f;
                }
            }
            #pragma unroll
            for (int kk = 0; kk < 9; ++kk) {
                float xk = xv[kk];
                const float4* wr = (const float4*)&wl[(c * 9 + kk) * 28];
                #pragma unroll
                for (int g = 0; g < 7; ++g) {
                    float4 wv = wr[g];
                    acc4[g].x += xk * wv.x;
                    acc4[g].y += xk * wv.y;
                    acc4[g].z += xk * wv.z;
                    acc4[g].w += xk * wv.w;
                }
            }
        }
    }

    const float* acc = (const float*)acc4;
    int idxp_base = (b * KK9) * HW + ho * WW + wo;
    #pragma unroll
    for (int k = 0; k < 9; ++k) {
        float dyv = acc[2 * k]     + offb[2 * k];
        float dxv = acc[2 * k + 1] + offb[2 * k + 1];
        float mv  = acc[18 + k]    + modb[k];
        float m   = 2.f / (1.f + expf(-mv));
        int idxp = idxp_base + k * HW;
        dy[idxp]   = dyv;
        dx[idxp]   = dxv;
        mask[idxp] = m;
    }
}

// ---------- kernel 2: bilinear sample -> bf16 LDS (XOR-swizzled) -> MFMA GEMM
// out tile per block: 128co x 64px ; 4 waves, wave wv owns co [wv*32, wv*32+32)
__global__ __launch_bounds__(256) void deform_main(
    const float* __restrict__ x,
    const float* __restrict__ dy, const float* __restrict__ dx,
    const float* __restrict__ mask,
    const unsigned short* __restrict__ afrag, const float* __restrict__ bias,
    float* __restrict__ out)
{
    __shared__ int4 sm4[64 * 16];   // 16 KiB: [px][c8 ^ (px&7)] 16B slots of 8 bf16

    const int tid  = threadIdx.x;
    const int lane = tid & 63;
    const int wv   = tid >> 6;
    const int l15  = lane & 15;
    const int l4   = lane >> 4;
    const int l7   = lane & 7;

    const int wstart = blockIdx.x * 48;   // 0 / 48 (overlap region writes identical values)
    const int ho     = blockIdx.y;
    const int b      = blockIdx.z;

    const int px = lane;                  // sampling: lane = pixel
    const int wo = wstart + px;

    f32x4 acc[2][4];
    const f32x4 zz = {0.f, 0.f, 0.f, 0.f};
    #pragma unroll
    for (int m = 0; m < 2; ++m)
        #pragma unroll
        for (int p = 0; p < 4; ++p) acc[m][p] = zz;

    const float* xb = x + (size_t)b * CIN * HW + (size_t)(wv * 32) * HW;
    const int pbase = (b * KK9) * HW + ho * WW + wo;

    for (int k = 0; k < 9; ++k) {
        // --- per-px corner addresses + (bilinear * valid * mask) weights (registers)
        int idxp = pbase + k * HW;
        float dyv = dy[idxp], dxv = dx[idxp], mv = mask[idxp];
        float ys = (float)(ho - 1 + (k / 3)) + dyv;
        float xs = (float)(wo - 1 + (k % 3)) + dxv;
        float fy = floorf(ys), fx = floorf(xs);
        int   y0 = (int)fy,   x0 = (int)fx;
        float ly = ys - fy,   lx = xs - fx;
        int   a0, a1, a2, a3;
        float w0, w1, w2, w3;
        {
            int yi0 = y0, yi1 = y0 + 1, xi0 = x0, xi1 = x0 + 1;
            bool vy0 = (unsigned)yi0 < HH, vy1 = (unsigned)yi1 < HH;
            bool vx0 = (unsigned)xi0 < WW, vx1 = (unsigned)xi1 < WW;
            a0 = (vy0 && vx0) ? yi0 * WW + xi0 : 0;
            a1 = (vy0 && vx1) ? yi0 * WW + xi1 : 0;
            a2 = (vy1 && vx0) ? yi1 * WW + xi0 : 0;
            a3 = (vy1 && vx1) ? yi1 * WW + xi1 : 0;
            w0 = (vy0 && vx0) ? (1.f - ly) * (1.f - lx) * mv : 0.f;
            w1 = (vy0 && vx1) ? (1.f - ly) * lx * mv : 0.f;
            w2 = (vy1 && vx0) ? ly * (1.f - lx) * mv : 0.f;
            w3 = (vy1 && vx1) ? ly * lx * mv : 0.f;
        }

        __syncthreads();   // prev-iter GEMM done reading sm

        // --- gather 32 channels (this wave's set) x 1 px into bf16 LDS
        #pragma unroll
        for (int g = 0; g < 4; ++g) {
            const float* xc = xb + (size_t)(g * 8) * HW;
            float v[8];
            #pragma unroll
            for (int h = 0; h < 8; ++h)
                v[h] = xc[h * HW + a0] * w0 + xc[h * HW + a1] * w1
                     + xc[h * HW + a2] * w2 + xc[h * HW + a3] * w3;
            int4 pk;
            pk.x = (int)(f2bf(v[0]) | (f2bf(v[1]) << 16));
            pk.y = (int)(f2bf(v[2]) | (f2bf(v[3]) << 16));
            pk.z = (int)(f2bf(v[4]) | (f2bf(v[5]) << 16));
            pk.w = (int)(f2bf(v[6]) | (f2bf(v[7]) << 16));
            sm4[px * 16 + ((wv * 4 + g) ^ l7)] = pk;
        }
        __syncthreads();

        // --- MFMA: acc[co-frag][px-frag] over 4 K-steps of 32 channels
        #pragma unroll
        for (int s = 0; s < 4; ++s) {
            const bf16x8* afv = (const bf16x8*)afrag + (size_t)((k * 4 + s) * 8) * 64;
            bf16x8 af0 = afv[(wv * 2 + 0) * 64 + lane];
            bf16x8 af1 = afv[(wv * 2 + 1) * 64 + lane];
            #pragma unroll
            for (int p = 0; p < 4; ++p) {
                bf16x8 bf = *(const bf16x8*)&sm4[(p * 16 + l15) * 16 + ((s * 4 + l4) ^ l7)];
                acc[0][p] = __builtin_amdgcn_mfma_f32_16x16x32_bf16(af0, bf, acc[0][p], 0, 0, 0);
                acc[1][p] = __builtin_amdgcn_mfma_f32_16x16x32_bf16(af1, bf, acc[1][p], 0, 0, 0);
            }
        }
    }

    // --- epilogue: + bias, store (row = co offset (l>>4)*4 + r, col = px l&15)
    #pragma unroll
    for (int m = 0; m < 2; ++m) {
        int co = wv * 32 + m * 16 + l4 * 4;
        #pragma unroll
        for (int p = 0; p < 4; ++p) {
            int wo2 = wstart + p * 16 + l15;
            size_t obase = ((size_t)(b * COUT + co) * HH + ho) * WW + wo2;
            #pragma unroll
            for (int r = 0; r < 4; ++r)
                out[obase + (size_t)r * HW] = acc[m][p][r] + bias[co + r];
        }
    }
}

extern "C" void kernel_launch(void* const* d_in, const int* in_sizes, int n_in,
                              void* d_out, int out_size, void* d_ws, size_t ws_size,
                              hipStream_t stream) {
    (void)in_sizes; (void)n_in; (void)out_size; (void)ws_size;
    const float* x    = (const float*)d_in[0];
    const float* offw = (const float*)d_in[1];
    const float* offb = (const float*)d_in[2];
    const float* modw = (const float*)d_in[3];
    const float* modb = (const float*)d_in[4];
    const float* w    = (const float*)d_in[5];
    const float* bias = (const float*)d_in[6];
    float* out = (float*)d_out;

    float* ws  = (float*)d_ws;
    float* dyp = ws;
    float* dxp = ws + (size_t)BKHW;
    float* mkp = ws + (size_t)2 * BKHW;
    unsigned short* afp = (unsigned short*)(ws + (size_t)3 * BKHW);  // 147456 bf16

    prep_afrag<<<576, 256, 0, stream>>>(w, afp);
    offmask_kernel<<<392, 256, 0, stream>>>(x, offw, offb, modw, modb, dyp, dxp, mkp);
    deform_main<<<dim3(2, 112, 8), 256, 0, stream>>>(x, dyp, dxp, mkp, afp, bias, out);
}

// Round 4
// 525.201 us; speedup vs baseline: 1.8444x; 1.4288x over previous
//
#include <hip/hip_runtime.h>
#include <hip/hip_bf16.h>
#include <math.h>

#define BATCH 8
#define CIN   128
#define COUT  128
#define HH    112
#define WW    112
#define HW    (HH*WW)          // 12544
#define KK9   9
#define BKHW  (BATCH*KK9*HW)   // 903168

typedef short  bf16x8 __attribute__((ext_vector_type(8)));
typedef float  f32x4  __attribute__((ext_vector_type(4)));

static __device__ __forceinline__ unsigned f2bf(float f) {
    union { float f; unsigned u; } v; v.f = f;
    unsigned r = v.u + 0x7FFF + ((v.u >> 16) & 1);
    return r >> 16;
}

// ---------- prep: x -> bf16 corner pairs  xp[b][c][y][x] = (bf16 x[y][x], bf16 x[y][x+1])
__global__ __launch_bounds__(256) void prep_xpair(const float* __restrict__ x,
                                                  unsigned* __restrict__ xp) {
    int id  = blockIdx.x * 256 + threadIdx.x;   // 12,845,056
    int col = id % WW;
    float a = x[id];
    float b = (col < WW - 1) ? x[id + 1] : 0.f;
    xp[id] = f2bf(a) | (f2bf(b) << 16);
}

// ---------- prep: w[co][c][3][3] -> bf16 MFMA A-fragment order (main GEMM)
__global__ __launch_bounds__(256) void prep_afrag(const float* __restrict__ w,
                                                  unsigned short* __restrict__ af) {
    int id   = blockIdx.x * 256 + threadIdx.x;   // 147456
    int j    = id & 7;
    int lane = (id >> 3) & 63;
    int m    = (id >> 9) & 7;
    int s    = (id >> 12) & 3;
    int k    = id >> 14;
    int co   = m * 16 + (lane & 15);
    int c    = s * 32 + (lane >> 4) * 8 + j;
    af[id] = (unsigned short)f2bf(w[(co * CIN + c) * 9 + k]);
}

// ---------- prep: offset/mod weights -> bf16 A-fragments, 27 ch padded to 32
__global__ __launch_bounds__(256) void prep_afragO(const float* __restrict__ offw,
                                                   const float* __restrict__ modw,
                                                   unsigned short* __restrict__ af) {
    int id   = blockIdx.x * 256 + threadIdx.x;   // 36864
    int j    = id & 7;
    int lane = (id >> 3) & 63;
    int m    = (id >> 9) & 1;
    int s    = (id >> 10) & 3;
    int kk   = id >> 12;                          // 0..8
    int ch   = m * 16 + (lane & 15);
    int c    = s * 32 + (lane >> 4) * 8 + j;
    float v = 0.f;
    if (ch < 18)      v = offw[(ch * CIN + c) * 9 + kk];
    else if (ch < 27) v = modw[((ch - 18) * CIN + c) * 9 + kk];
    af[id] = (unsigned short)f2bf(v);
}

// ---------- kernel 1: offset/mask conv via MFMA (M=32 pad 27, K=1152)
__global__ __launch_bounds__(256) void offmask_mfma(
    const float* __restrict__ x,
    const unsigned short* __restrict__ afO,
    const float* __restrict__ offb, const float* __restrict__ modb,
    float* __restrict__ dy, float* __restrict__ dx, float* __restrict__ mask)
{
    __shared__ int4 smo4[198 * 16];   // [ki 3][pxw 66] rows of 128 c bf16 (16B slots, XOR swz)

    const int tid  = threadIdx.x;
    const int lane = tid & 63;
    const int cset = tid >> 6;
    const int l15  = lane & 15;
    const int l4   = lane >> 4;
    const int wv   = tid >> 6;

    const int fid    = blockIdx.x;
    const int b      = fid & 7;
    const int r_     = fid >> 3;
    const int wstart = (r_ & 1) * 48;
    const int ho     = r_ >> 1;

    // ---- stage x neighborhood: 3 rows x 66 px x 128 c as bf16, [row][slot^ (pxw&7)]
    int* smoi = (int*)smo4;
    const size_t xbase = (size_t)(b * CIN + cset * 32) * HW;
    #pragma unroll
    for (int e = 0; e < 2; ++e) {
        int pxw = e ? (64 + lane) : lane;
        if (e && lane >= 2) break;
        int pxg = wstart - 1 + pxw;
        bool okc = (unsigned)pxg < (unsigned)WW;
        int pxc = okc ? pxg : 0;
        for (int ki = 0; ki < 3; ++ki) {
            int y = ho - 1 + ki;
            bool ok = okc && ((unsigned)y < (unsigned)HH);
            const float* base = x + xbase + (size_t)(ok ? y : 0) * WW + pxc;
            int R = ki * 66 + pxw;
            #pragma unroll 4
            for (int cp = 0; cp < 16; ++cp) {
                float va = ok ? base[(size_t)(cp * 2) * HW] : 0.f;
                float vb = ok ? base[(size_t)(cp * 2 + 1) * HW] : 0.f;
                unsigned pk = f2bf(va) | (f2bf(vb) << 16);
                int slot = (cset * 4 + (cp >> 2)) ^ (pxw & 7);
                smoi[(R * 16 + slot) * 4 + (cp & 3)] = (int)pk;
            }
        }
    }
    __syncthreads();

    // ---- MFMA: out[ch 32][px 16 per wave] over K = (c,kk)
    f32x4 acc0 = {0.f, 0.f, 0.f, 0.f}, acc1 = {0.f, 0.f, 0.f, 0.f};
    const bf16x8* afv = (const bf16x8*)afO;
    #pragma unroll 1
    for (int kk = 0; kk < 9; ++kk) {
        int ki = kk / 3, kj = kk % 3;
        int r  = wv * 16 + l15 + kj;       // pxw row in [0,66)
        int Rb = (ki * 66 + r) * 16;
        #pragma unroll
        for (int s = 0; s < 4; ++s) {
            bf16x8 a0 = afv[((kk * 4 + s) * 2 + 0) * 64 + lane];
            bf16x8 a1 = afv[((kk * 4 + s) * 2 + 1) * 64 + lane];
            bf16x8 bf = *(const bf16x8*)&smo4[Rb + ((s * 4 + l4) ^ (r & 7))];
            acc0 = __builtin_amdgcn_mfma_f32_16x16x32_bf16(a0, bf, acc0, 0, 0, 0);
            acc1 = __builtin_amdgcn_mfma_f32_16x16x32_bf16(a1, bf, acc1, 0, 0, 0);
        }
    }

    // ---- epilogue: ch = m*16 + l4*4 + r_i ; px = wstart + wv*16 + l15
    int px = wstart + wv * 16 + l15;
    int pix = ho * WW + px;
    #pragma unroll
    for (int m = 0; m < 2; ++m) {
        f32x4 A = m ? acc1 : acc0;
        #pragma unroll
        for (int ri = 0; ri < 4; ++ri) {
            int ch = m * 16 + l4 * 4 + ri;
            float val = A[ri];
            if (ch < 18) {
                int kq = ch >> 1;
                float o = val + offb[ch];
                int idxp = (b * KK9 + kq) * HW + pix;
                if (ch & 1) dx[idxp] = o; else dy[idxp] = o;
            } else if (ch < 27) {
                int kq = ch - 18;
                float t = val + modb[kq];
                mask[(b * KK9 + kq) * HW + pix] = 2.f / (1.f + expf(-t));
            }
        }
    }
}

// ---------- kernel 2: pipelined bilinear sample (bf16 pairs) -> LDS dbuf -> MFMA
__global__ __launch_bounds__(256, 3) void deform_main(
    const unsigned* __restrict__ xp,
    const float* __restrict__ dy, const float* __restrict__ dx,
    const float* __restrict__ mask,
    const unsigned short* __restrict__ afrag, const float* __restrict__ bias,
    float* __restrict__ out)
{
    __shared__ int4 sm4[2][64 * 16];   // 2 x 16 KiB: [px][c8 ^ (px&7)]

    const int tid  = threadIdx.x;
    const int lane = tid & 63;
    const int wv   = tid >> 6;
    const int l15  = lane & 15;
    const int l4   = lane >> 4;
    const int l7   = lane & 7;

    const int fid    = blockIdx.x;            // XCD swizzle: fid&7 = XCD = batch
    const int b      = fid & 7;
    const int r_     = fid >> 3;              // 0..223
    const int wstart = (r_ & 1) * 48;
    const int ho     = r_ >> 1;

    const int px = lane;
    const int wo = wstart + px;
    const int pbase = (b * KK9) * HW + ho * WW + wo;

    f32x4 acc[2][4];
    const f32x4 zz = {0.f, 0.f, 0.f, 0.f};
    #pragma unroll
    for (int m = 0; m < 2; ++m)
        #pragma unroll
        for (int p = 0; p < 4; ++p) acc[m][p] = zz;

    const unsigned* xb = xp + ((size_t)b * CIN + wv * 32) * HW;

    unsigned L[64];
    int   a0, a1, na0, na1;
    float w00, w01, w10, w11, nw00, nw01, nw10, nw11;
    float dyr, dxr, mvr;

    auto mkcorners = [&](int k, float dyv, float dxv, float mv,
                         int& A0, int& A1, float& W00, float& W01, float& W10, float& W11) {
        float ys = (float)(ho - 1 + k / 3) + dyv;
        float xs = (float)(wo - 1 + k % 3) + dxv;
        float fy = floorf(ys), fx = floorf(xs);
        int y0 = (int)fy, x0 = (int)fx;
        float ly = ys - fy, lx = xs - fx;
        bool vy0 = (unsigned)y0 < (unsigned)HH, vy1 = (unsigned)(y0 + 1) < (unsigned)HH;
        int r0 = vy0 ? y0 : 0, r1 = vy1 ? (y0 + 1) : 0;
        float wy0 = vy0 ? (1.f - ly) * mv : 0.f;
        float wy1 = vy1 ? ly * mv : 0.f;
        bool vx0 = (unsigned)x0 < (unsigned)WW;
        int xc = vx0 ? x0 : 0;
        float wxa = vx0 ? (1.f - lx) : ((x0 == -1) ? lx : 0.f);
        float wxb = (vx0 && (x0 < WW - 1)) ? lx : 0.f;
        A0 = r0 * WW + xc; A1 = r1 * WW + xc;
        W00 = wy0 * wxa; W01 = wy0 * wxb; W10 = wy1 * wxa; W11 = wy1 * wxb;
    };

    // prologue
    {
        float d0 = dy[pbase], e0 = dx[pbase], m0 = mask[pbase];
        mkcorners(0, d0, e0, m0, a0, a1, w00, w01, w10, w11);
        #pragma unroll
        for (int ci = 0; ci < 32; ++ci) {
            L[2 * ci]     = xb[(size_t)ci * HW + a0];
            L[2 * ci + 1] = xb[(size_t)ci * HW + a1];
        }
        dyr = dy[pbase + HW]; dxr = dx[pbase + HW]; mvr = mask[pbase + HW];
    }

    int cur = 0;
    for (int k = 0; k < 9; ++k) {
        // consume loads(k) -> bf16 pack -> LDS
        #pragma unroll
        for (int g = 0; g < 4; ++g) {
            float v[8];
            #pragma unroll
            for (int h = 0; h < 8; ++h) {
                int ci = g * 8 + h;
                unsigned d0 = L[2 * ci], d1 = L[2 * ci + 1];
                float f00 = __uint_as_float(d0 << 16);
                float f01 = __uint_as_float(d0 & 0xFFFF0000u);
                float f10 = __uint_as_float(d1 << 16);
                float f11 = __uint_as_float(d1 & 0xFFFF0000u);
                v[h] = f00 * w00 + f01 * w01 + f10 * w10 + f11 * w11;
            }
            int4 pk;
            pk.x = (int)(f2bf(v[0]) | (f2bf(v[1]) << 16));
            pk.y = (int)(f2bf(v[2]) | (f2bf(v[3]) << 16));
            pk.z = (int)(f2bf(v[4]) | (f2bf(v[5]) << 16));
            pk.w = (int)(f2bf(v[6]) | (f2bf(v[7]) << 16));
            sm4[cur][px * 16 + ((wv * 4 + g) ^ l7)] = pk;
        }
        // issue next tile's loads (stay in flight across the raw barrier)
        if (k < 8) {
            mkcorners(k + 1, dyr, dxr, mvr, na0, na1, nw00, nw01, nw10, nw11);
            #pragma unroll
            for (int ci = 0; ci < 32; ++ci) {
                L[2 * ci]     = xb[(size_t)ci * HW + na0];
                L[2 * ci + 1] = xb[(size_t)ci * HW + na1];
            }
            if (k < 7) {
                int ip = pbase + (k + 2) * HW;
                dyr = dy[ip]; dxr = dx[ip]; mvr = mask[ip];
            }
        }
        asm volatile("s_waitcnt lgkmcnt(0)" ::: "memory");
        __builtin_amdgcn_s_barrier();

        // MFMA(k) from sm4[cur] (loads(k+1) latency hides under this)
        #pragma unroll 1
        for (int s = 0; s < 4; ++s) {
            const bf16x8* afv = (const bf16x8*)afrag + (size_t)((k * 4 + s) * 8) * 64;
            bf16x8 af0 = afv[(wv * 2 + 0) * 64 + lane];
            bf16x8 af1 = afv[(wv * 2 + 1) * 64 + lane];
            #pragma unroll
            for (int p = 0; p < 4; ++p) {
                bf16x8 bf = *(const bf16x8*)&sm4[cur][(p * 16 + l15) * 16 + ((s * 4 + l4) ^ l7)];
                acc[0][p] = __builtin_amdgcn_mfma_f32_16x16x32_bf16(af0, bf, acc[0][p], 0, 0, 0);
                acc[1][p] = __builtin_amdgcn_mfma_f32_16x16x32_bf16(af1, bf, acc[1][p], 0, 0, 0);
            }
        }
        w00 = nw00; w01 = nw01; w10 = nw10; w11 = nw11;
        cur ^= 1;
    }

    // epilogue: + bias, store
    #pragma unroll
    for (int m = 0; m < 2; ++m) {
        int co = wv * 32 + m * 16 + l4 * 4;
        #pragma unroll
        for (int p = 0; p < 4; ++p) {
            int wo2 = wstart + p * 16 + l15;
            size_t obase = ((size_t)(b * COUT + co) * HH + ho) * WW + wo2;
            #pragma unroll
            for (int ri = 0; ri < 4; ++ri)
                out[obase + (size_t)ri * HW] = acc[m][p][ri] + bias[co + ri];
        }
    }
}

extern "C" void kernel_launch(void* const* d_in, const int* in_sizes, int n_in,
                              void* d_out, int out_size, void* d_ws, size_t ws_size,
                              hipStream_t stream) {
    (void)in_sizes; (void)n_in; (void)out_size; (void)ws_size;
    const float* x    = (const float*)d_in[0];
    const float* offw = (const float*)d_in[1];
    const float* offb = (const float*)d_in[2];
    const float* modw = (const float*)d_in[3];
    const float* modb = (const float*)d_in[4];
    const float* w    = (const float*)d_in[5];
    const float* bias = (const float*)d_in[6];
    float* out = (float*)d_out;

    float* ws  = (float*)d_ws;
    float* dyp = ws;
    float* dxp = ws + (size_t)BKHW;
    float* mkp = ws + (size_t)2 * BKHW;
    unsigned short* afp  = (unsigned short*)(ws + (size_t)3 * BKHW);            // 147456 bf16
    unsigned short* afOp = (unsigned short*)(ws + (size_t)3 * BKHW + 73728);    // 36864 bf16
    unsigned*       xpp  = (unsigned*)(ws + (size_t)3 * BKHW + 73728 + 18432);  // 12.85M dwords
    // total ws: ~62.6 MB

    prep_afragO<<<144, 256, 0, stream>>>(offw, modw, afOp);
    prep_afrag<<<576, 256, 0, stream>>>(w, afp);
    prep_xpair<<<50176, 256, 0, stream>>>(x, xpp);
    offmask_mfma<<<1792, 256, 0, stream>>>(x, afOp, offb, modb, dyp, dxp, mkp);
    deform_main<<<1792, 256, 0, stream>>>(xpp, dyp, dxp, mkp, afp, bias, out);
}

// Round 5
// 367.387 us; speedup vs baseline: 2.6366x; 1.4296x over previous
//
#include <hip/hip_runtime.h>
#include <hip/hip_bf16.h>
#include <math.h>

#define BATCH 8
#define CIN   128
#define COUT  128
#define HH    112
#define WW    112
#define HW    (HH*WW)          // 12544
#define KK9   9
#define BKHW  (BATCH*KK9*HW)   // 903168

typedef short  bf16x8 __attribute__((ext_vector_type(8)));
typedef float  f32x4  __attribute__((ext_vector_type(4)));

static __device__ __forceinline__ unsigned f2bf(float f) {
    union { float f; unsigned u; } v; v.f = f;
    unsigned r = v.u + 0x7FFF + ((v.u >> 16) & 1);
    return r >> 16;
}

// ---------- prep: x -> bf16 corner pairs  xp[b][c][y][x] = (bf16 x[y][x], bf16 x[y][x+1])
__global__ __launch_bounds__(256) void prep_xpair(const float* __restrict__ x,
                                                  unsigned* __restrict__ xp) {
    int id  = blockIdx.x * 256 + threadIdx.x;   // 12,845,056
    int col = id % WW;
    float a = x[id];
    float b = (col < WW - 1) ? x[id + 1] : 0.f;
    xp[id] = f2bf(a) | (f2bf(b) << 16);
}

// ---------- prep: w[co][c][3][3] -> bf16 MFMA A-fragment order (main GEMM)
__global__ __launch_bounds__(256) void prep_afrag(const float* __restrict__ w,
                                                  unsigned short* __restrict__ af) {
    int id   = blockIdx.x * 256 + threadIdx.x;   // 147456
    int j    = id & 7;
    int lane = (id >> 3) & 63;
    int m    = (id >> 9) & 7;
    int s    = (id >> 12) & 3;
    int k    = id >> 14;
    int co   = m * 16 + (lane & 15);
    int c    = s * 32 + (lane >> 4) * 8 + j;
    af[id] = (unsigned short)f2bf(w[(co * CIN + c) * 9 + k]);
}

// ---------- prep: offset/mod weights -> bf16 A-fragments, 27 ch padded to 32
__global__ __launch_bounds__(256) void prep_afragO(const float* __restrict__ offw,
                                                   const float* __restrict__ modw,
                                                   unsigned short* __restrict__ af) {
    int id   = blockIdx.x * 256 + threadIdx.x;   // 36864
    int j    = id & 7;
    int lane = (id >> 3) & 63;
    int m    = (id >> 9) & 1;
    int s    = (id >> 10) & 3;
    int kk   = id >> 12;                          // 0..8
    int ch   = m * 16 + (lane & 15);
    int c    = s * 32 + (lane >> 4) * 8 + j;
    float v = 0.f;
    if (ch < 18)      v = offw[(ch * CIN + c) * 9 + kk];
    else if (ch < 27) v = modw[((ch - 18) * CIN + c) * 9 + kk];
    af[id] = (unsigned short)f2bf(v);
}

// ---------- kernel 1: offset/mask conv via MFMA (M=32 pad 27, K=1152)
__global__ __launch_bounds__(256) void offmask_mfma(
    const float* __restrict__ x,
    const unsigned short* __restrict__ afO,
    const float* __restrict__ offb, const float* __restrict__ modb,
    float* __restrict__ dy, float* __restrict__ dx, float* __restrict__ mask)
{
    __shared__ int4 smo4[198 * 16];   // [ki 3][pxw 66] rows of 128 c bf16 (16B slots, XOR swz)

    const int tid  = threadIdx.x;
    const int lane = tid & 63;
    const int l15  = lane & 15;
    const int l4   = lane >> 4;
    const int wv   = tid >> 6;

    const int fid    = blockIdx.x;
    const int b      = fid & 7;
    const int r_     = fid >> 3;
    const int wstart = (r_ & 1) * 48;
    const int ho     = r_ >> 1;

    // ---- stage x neighborhood: flat coalesced split, no divergent tail.
    // it = (ki*64 + g)*66 + pxw ; channels 2g,2g+1 ; consecutive tid -> consecutive pxw
    int* smoi = (int*)smo4;
    for (int it = tid; it < 3 * 64 * 66; it += 256) {
        int pxw = it % 66;
        int kg  = it / 66;
        int ki  = kg >> 6;
        int g   = kg & 63;
        int y   = ho - 1 + ki;
        int pxg = wstart - 1 + pxw;
        bool ok = ((unsigned)y < (unsigned)HH) && ((unsigned)pxg < (unsigned)WW);
        const float* base = x + (size_t)(b * CIN + 2 * g) * HW + (ok ? (y * WW + pxg) : 0);
        float va = ok ? base[0]  : 0.f;
        float vb = ok ? base[HW] : 0.f;
        unsigned pk = f2bf(va) | (f2bf(vb) << 16);
        smoi[((ki * 66 + pxw) * 16 + ((g >> 2) ^ (pxw & 7))) * 4 + (g & 3)] = (int)pk;
    }
    __syncthreads();

    // ---- MFMA: out[ch 32][px 16 per wave] over K = (c,kk)
    f32x4 acc0 = {0.f, 0.f, 0.f, 0.f}, acc1 = {0.f, 0.f, 0.f, 0.f};
    const bf16x8* afv = (const bf16x8*)afO;
    #pragma unroll 1
    for (int kk = 0; kk < 9; ++kk) {
        int ki = kk / 3, kj = kk % 3;
        int r  = wv * 16 + l15 + kj;       // pxw row in [0,66)
        int Rb = (ki * 66 + r) * 16;
        #pragma unroll
        for (int s = 0; s < 4; ++s) {
            bf16x8 a0 = afv[((kk * 4 + s) * 2 + 0) * 64 + lane];
            bf16x8 a1 = afv[((kk * 4 + s) * 2 + 1) * 64 + lane];
            bf16x8 bf = *(const bf16x8*)&smo4[Rb + ((s * 4 + l4) ^ (r & 7))];
            acc0 = __builtin_amdgcn_mfma_f32_16x16x32_bf16(a0, bf, acc0, 0, 0, 0);
            acc1 = __builtin_amdgcn_mfma_f32_16x16x32_bf16(a1, bf, acc1, 0, 0, 0);
        }
    }

    // ---- epilogue
    int px = wstart + wv * 16 + l15;
    int pix = ho * WW + px;
    #pragma unroll
    for (int m = 0; m < 2; ++m) {
        f32x4 A = m ? acc1 : acc0;
        #pragma unroll
        for (int ri = 0; ri < 4; ++ri) {
            int ch = m * 16 + l4 * 4 + ri;
            float val = A[ri];
            if (ch < 18) {
                int kq = ch >> 1;
                float o = val + offb[ch];
                int idxp = (b * KK9 + kq) * HW + pix;
                if (ch & 1) dx[idxp] = o; else dy[idxp] = o;
            } else if (ch < 27) {
                int kq = ch - 18;
                float t = val + modb[kq];
                mask[(b * KK9 + kq) * HW + pix] = 2.f / (1.f + expf(-t));
            }
        }
    }
}

// ---------- kernel 2: 4-sub-phase rotating-chunk pipeline, depth-2 gather prefetch
#define GATHER(LARR, CBASE, A0, A1)                                  \
    { _Pragma("unroll")                                              \
      for (int h = 0; h < 8; ++h) {                                  \
        LARR[2*h]   = xbw[(size_t)((CBASE) + h) * HW + (A0)];        \
        LARR[2*h+1] = xbw[(size_t)((CBASE) + h) * HW + (A1)];        \
      } }

#define PACKST(S, LARR)                                              \
    { float v[8];                                                    \
      _Pragma("unroll")                                              \
      for (int h = 0; h < 8; ++h) {                                  \
        unsigned d0 = LARR[2*h], d1 = LARR[2*h+1];                   \
        float f00 = __uint_as_float(d0 << 16);                       \
        float f01 = __uint_as_float(d0 & 0xFFFF0000u);               \
        float f10 = __uint_as_float(d1 << 16);                       \
        float f11 = __uint_as_float(d1 & 0xFFFF0000u);               \
        v[h] = f00*w00 + f01*w01 + f10*w10 + f11*w11;                \
      }                                                              \
      int4 pk;                                                       \
      pk.x = (int)(f2bf(v[0]) | (f2bf(v[1]) << 16));                 \
      pk.y = (int)(f2bf(v[2]) | (f2bf(v[3]) << 16));                 \
      pk.z = (int)(f2bf(v[4]) | (f2bf(v[5]) << 16));                 \
      pk.w = (int)(f2bf(v[6]) | (f2bf(v[7]) << 16));                 \
      sm4[px * 16 + (((S) * 4 + wv) ^ l7)] = pk; }

#define BARRIER asm volatile("s_waitcnt lgkmcnt(0)\n\ts_barrier" ::: "memory")

#define MFMAP(S)                                                     \
    { _Pragma("unroll")                                              \
      for (int p = 0; p < 4; ++p) {                                  \
        bf16x8 bf = *(const bf16x8*)&sm4[(p*16 + l15)*16 + (((S)*4 + l4) ^ l7)]; \
        acc[0][p] = __builtin_amdgcn_mfma_f32_16x16x32_bf16(af[(S)*2+0], bf, acc[0][p], 0, 0, 0); \
        acc[1][p] = __builtin_amdgcn_mfma_f32_16x16x32_bf16(af[(S)*2+1], bf, acc[1][p], 0, 0, 0); \
      } }

__global__ __launch_bounds__(256) void deform_main(
    const unsigned* __restrict__ xp,
    const float* __restrict__ dy, const float* __restrict__ dx,
    const float* __restrict__ mask,
    const unsigned short* __restrict__ afrag, const float* __restrict__ bias,
    float* __restrict__ out)
{
    __shared__ int4 sm4[64 * 16];   // 16 KiB, single buffer: 4 chunk slot-sets rotate

    const int tid  = threadIdx.x;
    const int lane = tid & 63;
    const int wv   = tid >> 6;
    const int l15  = lane & 15;
    const int l4   = lane >> 4;
    const int l7   = lane & 7;

    const int fid    = blockIdx.x;            // XCD swizzle: fid&7 = XCD = batch
    const int b      = fid & 7;
    const int r_     = fid >> 3;              // 0..223
    const int wstart = (r_ & 1) * 48;
    const int ho     = r_ >> 1;

    const int px = lane;
    const int wo = wstart + px;
    const int pbase = (b * KK9) * HW + ho * WW + wo;

    f32x4 acc[2][4];
    const f32x4 zz = {0.f, 0.f, 0.f, 0.f};
    #pragma unroll
    for (int m = 0; m < 2; ++m)
        #pragma unroll
        for (int p = 0; p < 4; ++p) acc[m][p] = zz;

    // wave's gather base: 8 channels starting at wv*8 (chunk adds s*32)
    const unsigned* xbw = xp + ((size_t)b * CIN + wv * 8) * HW;

    unsigned L0[16], L1[16];
    bf16x8 af[8];
    int   a0, a1, na0, na1;
    float w00, w01, w10, w11, nw00, nw01, nw10, nw11;
    float dyr, dxr, mvr;

    auto mkcorners = [&](int k, float dyv, float dxv, float mv,
                         int& A0, int& A1, float& W00, float& W01, float& W10, float& W11) {
        float ys = (float)(ho - 1 + k / 3) + dyv;
        float xs = (float)(wo - 1 + k % 3) + dxv;
        float fy = floorf(ys), fx = floorf(xs);
        int y0 = (int)fy, x0 = (int)fx;
        float ly = ys - fy, lx = xs - fx;
        bool vy0 = (unsigned)y0 < (unsigned)HH, vy1 = (unsigned)(y0 + 1) < (unsigned)HH;
        int r0 = vy0 ? y0 : 0, r1 = vy1 ? (y0 + 1) : 0;
        float wy0 = vy0 ? (1.f - ly) * mv : 0.f;
        float wy1 = vy1 ? ly * mv : 0.f;
        bool vx0 = (unsigned)x0 < (unsigned)WW;
        int xc = vx0 ? x0 : 0;
        float wxa = vx0 ? (1.f - lx) : ((x0 == -1) ? lx : 0.f);
        float wxb = (vx0 && (x0 < WW - 1)) ? lx : 0.f;
        A0 = r0 * WW + xc; A1 = r1 * WW + xc;
        W00 = wy0 * wxa; W01 = wy0 * wxb; W10 = wy1 * wxa; W11 = wy1 * wxb;
    };

    // ---- prologue: corners(0), dym(1), issue chunks (0,0),(0,1)
    {
        float d0 = dy[pbase], e0 = dx[pbase], m0 = mask[pbase];
        mkcorners(0, d0, e0, m0, a0, a1, w00, w01, w10, w11);
        int ip = pbase + HW;
        dyr = dy[ip]; dxr = dx[ip]; mvr = mask[ip];
    }
    GATHER(L0, 0,  a0, a1)
    GATHER(L1, 32, a0, a1)

    #pragma unroll 1
    for (int k = 0; k < 9; ++k) {
        // ---- phase 0: pack (k,0); load af(k); issue (k,2)
        PACKST(0, L0)
        {
            const bf16x8* afb = (const bf16x8*)afrag + (size_t)k * 32 * 64;
            #pragma unroll
            for (int s2 = 0; s2 < 4; ++s2) {
                af[s2 * 2 + 0] = afb[(s2 * 8 + wv * 2 + 0) * 64 + lane];
                af[s2 * 2 + 1] = afb[(s2 * 8 + wv * 2 + 1) * 64 + lane];
            }
        }
        GATHER(L0, 64, a0, a1)
        BARRIER;
        MFMAP(0)

        // ---- phase 1: pack (k,1); issue (k,3)
        PACKST(1, L1)
        GATHER(L1, 96, a0, a1)
        BARRIER;
        MFMAP(1)

        // ---- phase 2: pack (k,2); corners(k+1); issue (k+1,0); prefetch dym(k+2)
        PACKST(2, L0)
        if (k < 8) {
            mkcorners(k + 1, dyr, dxr, mvr, na0, na1, nw00, nw01, nw10, nw11);
            GATHER(L0, 0, na0, na1)
            if (k < 7) {
                int ip = pbase + (k + 2) * HW;
                dyr = dy[ip]; dxr = dx[ip]; mvr = mask[ip];
            }
        }
        BARRIER;
        MFMAP(2)

        // ---- phase 3: pack (k,3); issue (k+1,1)
        PACKST(3, L1)
        if (k < 8) GATHER(L1, 32, na0, na1)
        BARRIER;
        MFMAP(3)

        if (k < 8) {
            a0 = na0; a1 = na1;
            w00 = nw00; w01 = nw01; w10 = nw10; w11 = nw11;
        }
    }

    // ---- epilogue: + bias, store
    #pragma unroll
    for (int m = 0; m < 2; ++m) {
        int co = wv * 32 + m * 16 + l4 * 4;
        #pragma unroll
        for (int p = 0; p < 4; ++p) {
            int wo2 = wstart + p * 16 + l15;
            size_t obase = ((size_t)(b * COUT + co) * HH + ho) * WW + wo2;
            #pragma unroll
            for (int ri = 0; ri < 4; ++ri)
                out[obase + (size_t)ri * HW] = acc[m][p][ri] + bias[co + ri];
        }
    }
}

extern "C" void kernel_launch(void* const* d_in, const int* in_sizes, int n_in,
                              void* d_out, int out_size, void* d_ws, size_t ws_size,
                              hipStream_t stream) {
    (void)in_sizes; (void)n_in; (void)out_size; (void)ws_size;
    const float* x    = (const float*)d_in[0];
    const float* offw = (const float*)d_in[1];
    const float* offb = (const float*)d_in[2];
    const float* modw = (const float*)d_in[3];
    const float* modb = (const float*)d_in[4];
    const float* w    = (const float*)d_in[5];
    const float* bias = (const float*)d_in[6];
    float* out = (float*)d_out;

    float* ws  = (float*)d_ws;
    float* dyp = ws;
    float* dxp = ws + (size_t)BKHW;
    float* mkp = ws + (size_t)2 * BKHW;
    unsigned short* afp  = (unsigned short*)(ws + (size_t)3 * BKHW);            // 147456 bf16
    unsigned short* afOp = (unsigned short*)(ws + (size_t)3 * BKHW + 73728);    // 36864 bf16
    unsigned*       xpp  = (unsigned*)(ws + (size_t)3 * BKHW + 73728 + 18432);  // 12.85M dwords
    // total ws: ~62.6 MB

    prep_afragO<<<144, 256, 0, stream>>>(offw, modw, afOp);
    prep_afrag<<<576, 256, 0, stream>>>(w, afp);
    prep_xpair<<<50176, 256, 0, stream>>>(x, xpp);
    offmask_mfma<<<1792, 256, 0, stream>>>(x, afOp, offb, modb, dyp, dxp, mkp);
    deform_main<<<1792, 256, 0, stream>>>(xpp, dyp, dxp, mkp, afp, bias, out);
}